// Round 11
// baseline (169.356 us; speedup 1.0000x reference)
//
#include <hip/hip_runtime.h>

// GSKAN layer: out[b,q] = sum_p prelu(x[b,p] + eps[q]) * Lam[p,q]
// prelu(s) = c1*s + c2*|s|,  c1 = (1+a)/2, c2 = (1-a)/2  (|s| = free VOP3 modifier)
//
// R11 = R10 (XCD-aware placement, FETCH==unique bytes proven) + pinned
// double-buffer pipeline. R10 falsified the memory-traffic theory (FETCH -5.4x,
// time flat): the kernel is anti-phase serialized -- each wave alternates
// {8 ds_read -> lgkmcnt(0) -> 192 VALU} so the co-saturated LDS pipe and VALU
// (12288 cyc each per CU-chunk) run alternately, not concurrently, and VGPR=60
// gives the scheduler no room. Fix: next chunk's global loads are issued BEFORE
// the FMA block and pinned with sched_barrier(0) (cannot be re-sunk); their
// vmcnt-wait lands at the ds_write after compute. 1 barrier/chunk. The
// in-flight registers also push the allocator off the 60-VGPR trap naturally.

#define PCHUNK 32
#define XS_STRIDE 36   // 4 rows/thread -> distinct bank quads, 2-way alias only

__global__ __launch_bounds__(256) void gskan_partial_kernel(
    const float* __restrict__ X,     // [B][n_in]
    const float* __restrict__ Lam,   // [n_in][n_out]
    const float* __restrict__ Eps,   // [n_out]
    const float* __restrict__ Aw,    // [1]
    float* __restrict__ Part,        // [nsplit][B][n_out]
    int B, int n_in, int n_out, int p_per_split,
    int nq, int nb, int nsplit)
{
    __shared__ float xs[2][64 * XS_STRIDE];   // 2 x 9.2 KB
    __shared__ float ls[2][PCHUNK * 64];      // 2 x 8 KB

    // ---- XCD-aware decode: class g&7 owns one z-slice (all q,b for it) ----
    int q_tile, b_tile, zsp;
    {
        const int g = blockIdx.x;
        const int per_z = nq * nb;
        if ((nsplit & 7) == 0 || nsplit * per_z == 1024) {
            const int cls = g & 7;
            const int idx = g >> 3;
            zsp    = cls + 8 * (idx / per_z);
            const int r = idx % per_z;
            q_tile = r % nq;
            b_tile = r / nq;
        } else {
            zsp    = g / per_z;
            const int r = g % per_z;
            q_tile = r % nq;
            b_tile = r / nq;
        }
    }

    const int tid = threadIdx.x;
    const int qg  = tid & 15;
    const int bl  = tid >> 4;

    const int q0 = q_tile * 64;
    const int b0 = b_tile * 64;
    const int p_begin = zsp * p_per_split;
    int p_end = p_begin + p_per_split;
    if (p_end > n_in) p_end = n_in;

    const float a  = Aw[0];
    const float c1 = 0.5f * (1.0f + a);
    const float c2 = 0.5f * (1.0f - a);

    const float4 ev = *reinterpret_cast<const float4*>(Eps + q0 + qg * 4);
    const float ee[4] = {ev.x, ev.y, ev.z, ev.w};

    float acc1[4][4] = {};
    float acc2[4][4] = {};

    // staging assignments
    const int srowX = tid >> 3, spgX = tid & 7;    // X: rows +0 / +32
    const int srowL = tid >> 4, sc4L = tid & 15;   // Lam: rows +0 / +16

    const float* Xr0 = X + (size_t)(b0 + srowX) * n_in + spgX * 4;
    const float* Xr1 = X + (size_t)(b0 + srowX + 32) * n_in + spgX * 4;
    const float* Lr0 = Lam + (size_t)srowL * n_out + q0 + sc4L * 4;
    const float* Lr1 = Lam + (size_t)(srowL + 16) * n_out + q0 + sc4L * 4;

    // prologue: stage chunk 0 into buffer 0
    {
        const int pc = p_begin;
        float4 v0 = *reinterpret_cast<const float4*>(Xr0 + pc);
        float4 v1 = *reinterpret_cast<const float4*>(Xr1 + pc);
        float4 l0 = *reinterpret_cast<const float4*>(Lr0 + (size_t)pc * n_out);
        float4 l1 = *reinterpret_cast<const float4*>(Lr1 + (size_t)pc * n_out);
        *reinterpret_cast<float4*>(&xs[0][srowX * XS_STRIDE + spgX * 4]) = v0;
        *reinterpret_cast<float4*>(&xs[0][(srowX + 32) * XS_STRIDE + spgX * 4]) = v1;
        *reinterpret_cast<float4*>(&ls[0][srowL * 64 + sc4L * 4]) = l0;
        *reinterpret_cast<float4*>(&ls[0][(srowL + 16) * 64 + sc4L * 4]) = l1;
    }
    __syncthreads();

    for (int c = 0;; ++c) {
        const int pc_next = p_begin + (c + 1) * PCHUNK;
        const bool hasnext = pc_next < p_end;

        float4 nx0, nx1, nl0, nl1;
        if (hasnext) {   // issue next-chunk global loads NOW; waits land post-FMA
            nx0 = *reinterpret_cast<const float4*>(Xr0 + pc_next);
            nx1 = *reinterpret_cast<const float4*>(Xr1 + pc_next);
            nl0 = *reinterpret_cast<const float4*>(Lr0 + (size_t)pc_next * n_out);
            nl1 = *reinterpret_cast<const float4*>(Lr1 + (size_t)pc_next * n_out);
        }
        __builtin_amdgcn_sched_barrier(0);   // loads cannot sink below this

        const float* xcur = xs[c & 1];
        const float* lcur = ls[c & 1];
        #pragma unroll
        for (int p = 0; p < PCHUNK; p += 4) {
            float4 xv[4];
            #pragma unroll
            for (int i = 0; i < 4; ++i)
                xv[i] = *reinterpret_cast<const float4*>(
                    &xcur[(bl * 4 + i) * XS_STRIDE + p]);

            #pragma unroll
            for (int pp = 0; pp < 4; ++pp) {
                float4 lv = *reinterpret_cast<const float4*>(
                    &lcur[(p + pp) * 64 + qg * 4]);
                const float le[4] = {lv.x, lv.y, lv.z, lv.w};
                #pragma unroll
                for (int i = 0; i < 4; ++i) {
                    const float xe = (pp == 0) ? xv[i].x :
                                     (pp == 1) ? xv[i].y :
                                     (pp == 2) ? xv[i].z : xv[i].w;
                    #pragma unroll
                    for (int j = 0; j < 4; ++j) {
                        const float s = xe + ee[j];
                        acc1[i][j] = fmaf(s,        le[j], acc1[i][j]);
                        acc2[i][j] = fmaf(fabsf(s), le[j], acc2[i][j]);
                    }
                }
            }
        }

        if (!hasnext) break;
        const int nxt = (c + 1) & 1;
        *reinterpret_cast<float4*>(&xs[nxt][srowX * XS_STRIDE + spgX * 4]) = nx0;
        *reinterpret_cast<float4*>(&xs[nxt][(srowX + 32) * XS_STRIDE + spgX * 4]) = nx1;
        *reinterpret_cast<float4*>(&ls[nxt][srowL * 64 + sc4L * 4]) = nl0;
        *reinterpret_cast<float4*>(&ls[nxt][(srowL + 16) * 64 + sc4L * 4]) = nl1;
        __syncthreads();   // single barrier per chunk
    }

    float* P = Part + (size_t)zsp * B * n_out;
    #pragma unroll
    for (int i = 0; i < 4; ++i) {
        const int b = b0 + bl * 4 + i;
        float4 o;
        o.x = c1 * acc1[i][0] + c2 * acc2[i][0];
        o.y = c1 * acc1[i][1] + c2 * acc2[i][1];
        o.z = c1 * acc1[i][2] + c2 * acc2[i][2];
        o.w = c1 * acc1[i][3] + c2 * acc2[i][3];
        *reinterpret_cast<float4*>(P + (size_t)b * n_out + q0 + qg * 4) = o;
    }
}

__global__ __launch_bounds__(256) void gskan_combine_kernel(
    const float* __restrict__ Part, float* __restrict__ Y, int n, int nsplit)
{
    int i = (blockIdx.x * 256 + threadIdx.x) * 4;
    if (i >= n) return;
    float4 acc = *reinterpret_cast<const float4*>(Part + i);
    for (int s = 1; s < nsplit; ++s) {
        float4 v = *reinterpret_cast<const float4*>(Part + (size_t)s * n + i);
        acc.x += v.x; acc.y += v.y; acc.z += v.z; acc.w += v.w;
    }
    *reinterpret_cast<float4*>(Y + i) = acc;
}

extern "C" void kernel_launch(void* const* d_in, const int* in_sizes, int n_in_args,
                              void* d_out, int out_size, void* d_ws, size_t ws_size,
                              hipStream_t stream)
{
    (void)n_in_args; (void)out_size;

    const float* x = (const float*)d_in[0];

    struct LayerP { const float *Lam, *Eps, *Aw; int n_in, n_out; };
    LayerP layers[4];
    for (int i = 0; i < 4; ++i) {
        layers[i].Lam   = (const float*)d_in[1 + 3 * i];
        layers[i].Eps   = (const float*)d_in[2 + 3 * i];
        layers[i].Aw    = (const float*)d_in[3 + 3 * i];
        layers[i].n_out = in_sizes[2 + 3 * i];
        layers[i].n_in  = in_sizes[1 + 3 * i] / layers[i].n_out;
    }
    const int B = in_sizes[0] / layers[0].n_in;

    // ws layout: [Part: 16MB][yA: 2MB][yB: 2MB]
    char* ws = (char*)d_ws;
    float* Part = (float*)ws;
    float* yA   = (float*)(ws + (size_t)(16u << 20));
    float* yB   = (float*)(ws + (size_t)(18u << 20));
    const bool have_ws = ws_size >= (size_t)(20u << 20);

    const float* cur = x;
    for (int i = 0; i < 4; ++i) {
        const LayerP& ly = layers[i];
        const int nq = ly.n_out / 64;
        const int nb = B / 64;

        int nsplit = 1;
        if (have_ws) {
            nsplit = 1024 / (nq * nb);              // exactly 1024 blocks = 4/CU
            if (nsplit < 1) nsplit = 1;
            int max_split = ly.n_in / PCHUNK;
            if (nsplit > max_split) nsplit = max_split;
        }
        int p_per = ((ly.n_in + nsplit * PCHUNK - 1) / (nsplit * PCHUNK)) * PCHUNK;
        nsplit = (ly.n_in + p_per - 1) / p_per;

        // Part capacity guard: nsplit * B * n_out floats must fit 16MB
        while ((size_t)nsplit * B * ly.n_out * 4 > ((size_t)16u << 20)) nsplit--;
        if (nsplit < 1) nsplit = 1;
        p_per = ((ly.n_in + nsplit * PCHUNK - 1) / (nsplit * PCHUNK)) * PCHUNK;
        nsplit = (ly.n_in + p_per - 1) / p_per;

        float* Y = (i == 3) ? (float*)d_out : ((i % 2 == 0) ? yA : yB);
        float* dst = (nsplit == 1) ? Y : Part;

        dim3 grid(nq * nb * nsplit), block(256);
        hipLaunchKernelGGL(gskan_partial_kernel, grid, block, 0, stream,
                           cur, ly.Lam, ly.Eps, ly.Aw, dst,
                           B, ly.n_in, ly.n_out, p_per, nq, nb, nsplit);

        if (nsplit > 1) {
            const int n = B * ly.n_out;
            dim3 cg((n / 4 + 255) / 256), cb(256);
            hipLaunchKernelGGL(gskan_combine_kernel, cg, cb, 0, stream, Part, Y, n, nsplit);
        }
        cur = Y;
    }
}